// Round 1
// 173.482 us; speedup vs baseline: 1.1378x; 1.1378x over previous
//
#include <hip/hip_runtime.h>
#include <math.h>

#define B 8
#define N 1024
#define L 16
#define D 256
#define H 4
#define DH 64
#define NLAYERS 2
#define V 32000

typedef __attribute__((ext_vector_type(8))) short short8;
typedef __attribute__((ext_vector_type(4))) float f32x4;

union U8 { uint4 u; short8 s; };

__device__ inline unsigned short f2bf(float x) {
    unsigned u = __float_as_uint(x);
    u = (u + 0x7fff + ((u >> 16) & 1)) >> 16;  // RNE
    return (unsigned short)u;
}
__device__ inline float bf2f(unsigned short x) {
    return __uint_as_float(((unsigned)x) << 16);
}

// -------- layouts --------
// h_sw  [b][n>>4][d>>5][n&15][d&31]  bf16  residual stream
// WT_sw [lh][d>>5][dh][d&31]         bf16  (B operand of Wh MFMA)
// WhT   [bh][m>>5][dh][m&31]         bf16  (B operand of attn MFMA)
// pack  [b][n][m/64]                 u64 adjacency (+self-loop)

#define PACK_BLK 2048
#define WT_BLK   (NLAYERS * H * 4)   // 32
#define PRE_GRID (PACK_BLK + WT_BLK + 1)

// ---- k_pre: packadj + WT transpose (both layers) + len ----
__global__ __launch_bounds__(256) void k_pre(const int* __restrict__ adj,
                                             const float* __restrict__ W,
                                             const int* __restrict__ len,
                                             unsigned long long* __restrict__ pack,
                                             unsigned short* __restrict__ WT_sw,
                                             float* __restrict__ out_len) {
    int bid = blockIdx.x;
    int t = threadIdx.x;
    if (bid < PACK_BLK) {
        int row = bid * 4 + (t >> 6);  // bn
        int lane = t & 63;
        int n = row & (N - 1);
        const int* arow = adj + (long)row * N;
        unsigned long long* prow = pack + (size_t)row * 16;
        int g16 = lane & 15;
#pragma unroll
        for (int it = 0; it < 4; ++it) {
            int m0 = it * 256 + lane * 4;
            int4 a = *(const int4*)(arow + m0);
            unsigned nib = (unsigned)((a.x != 0) || (m0 == n))
                         | ((unsigned)((a.y != 0) || (m0 + 1 == n)) << 1)
                         | ((unsigned)((a.z != 0) || (m0 + 2 == n)) << 2)
                         | ((unsigned)((a.w != 0) || (m0 + 3 == n)) << 3);
            unsigned long long v = (unsigned long long)nib << (g16 * 4);
            v |= __shfl_xor(v, 1, 64);
            v |= __shfl_xor(v, 2, 64);
            v |= __shfl_xor(v, 4, 64);
            v |= __shfl_xor(v, 8, 64);
            if (g16 == 0) prow[it * 4 + (lane >> 4)] = v;
        }
    } else if (bid < PACK_BLK + WT_BLK) {
        int idx = bid - PACK_BLK;
        int lh = idx >> 2, q = idx & 3;
        const float* Wl = W + (size_t)lh * D * DH;
        int dh = t & 63;
        int d0 = q * 64 + (t >> 6) * 16;
#pragma unroll
        for (int i = 0; i < 16; ++i) {
            int d = d0 + i;
            WT_sw[(((size_t)lh * 8 + (d >> 5)) * 64 + dh) * 32 + (d & 31)] = f2bf(Wl[(size_t)d * DH + dh]);
        }
    } else {
        if (t < B) out_len[t] = (float)len[t];
    }
}

// ---- shared per-wave tile: Wh = h(16x256) @ W(head), write WhT + srcv/dstv ----
// hA: LDS [kc=8][row=16][32] bf16 (same inner layout as h_sw tile)
__device__ inline void wh_tile(const unsigned short* __restrict__ hA,
                               const unsigned short* __restrict__ WT_l,
                               const float* __restrict__ asrc_l,
                               const float* __restrict__ adst_l,
                               unsigned short* __restrict__ WhT_out,
                               float* __restrict__ srcv_out,
                               float* __restrict__ dstv_out,
                               int b, int n0, int hh, int lane) {
    int rowLane = lane & 15, quad = lane >> 4;
    int bh = b * H + hh;
    const unsigned short* abase = hA + rowLane * 32 + quad * 8;
    const unsigned short* bbase = WT_l + (size_t)hh * 16384 + rowLane * 32 + quad * 8;
    f32x4 acc[4] = {};
#pragma unroll
    for (int kc = 0; kc < 8; ++kc) {
        short8 af = *(const short8*)(abase + kc * 512);
#pragma unroll
        for (int c = 0; c < 4; ++c) {
            short8 bf = *(const short8*)(bbase + (size_t)kc * 2048 + c * 512);
            acc[c] = __builtin_amdgcn_mfma_f32_16x16x32_bf16(af, bf, acc[c], 0, 0, 0);
        }
    }
    // D[row=quad*4+r][dh=c*16+rowLane]; rows are 4 consecutive m -> direct ushort4 into WhT
    int m0 = n0 + quad * 4;
    float ps[4] = {0.f, 0.f, 0.f, 0.f}, pd[4] = {0.f, 0.f, 0.f, 0.f};
#pragma unroll
    for (int c = 0; c < 4; ++c) {
        int dh = c * 16 + rowLane;
        ushort4 o;
        o.x = f2bf(acc[c][0]); o.y = f2bf(acc[c][1]);
        o.z = f2bf(acc[c][2]); o.w = f2bf(acc[c][3]);
        *(ushort4*)&WhT_out[(((size_t)bh * 32 + (m0 >> 5)) * 64 + dh) * 32 + (m0 & 31)] = o;
        float as = asrc_l[hh * DH + dh];
        float ad = adst_l[hh * DH + dh];
#pragma unroll
        for (int r = 0; r < 4; ++r) { ps[r] += acc[c][r] * as; pd[r] += acc[c][r] * ad; }
    }
#pragma unroll
    for (int off = 1; off < 16; off <<= 1) {
#pragma unroll
        for (int r = 0; r < 4; ++r) {
            ps[r] += __shfl_xor(ps[r], off, 64);
            pd[r] += __shfl_xor(pd[r], off, 64);
        }
    }
    if (rowLane == 0) {
#pragma unroll
        for (int r = 0; r < 4; ++r) {
            srcv_out[bh * N + m0 + r] = ps[r];
            dstv_out[bh * N + m0 + r] = pd[r];
        }
    }
}

// ---- k_feat: gather/mean -> h_sw + hA, then layer-0 Wh fused (waves 0..3 = heads) ----
__global__ __launch_bounds__(1024) void k_feat(const float* __restrict__ emb,
                                               const int* __restrict__ nodes,
                                               unsigned short* __restrict__ h_sw,
                                               const unsigned short* __restrict__ WT0,
                                               const float* __restrict__ asrc0,
                                               const float* __restrict__ adst0,
                                               unsigned short* __restrict__ WhT0,
                                               float* __restrict__ srcv0,
                                               float* __restrict__ dstv0) {
    __shared__ __align__(16) int nodesLds[256];
    __shared__ __align__(16) unsigned short hA[8 * 16 * 32];
    int tid = threadIdx.x;
    int bt = blockIdx.x;
    int b = bt >> 6, nt = bt & 63, n0 = nt * 16;
    if (tid < 256) nodesLds[tid] = nodes[(size_t)(b * N + n0) * L + tid];
    __syncthreads();
    int w = tid >> 6, lane = tid & 63;   // w = row in tile (16 rows, 16 waves)
    int d4 = lane * 4;
    const int* np = nodesLds + w * L;
    float4 s = make_float4(0.f, 0.f, 0.f, 0.f);
#pragma unroll
    for (int l = 0; l < L; ++l) {
        float4 v = *(const float4*)&emb[(size_t)np[l] * D + d4];
        s.x += v.x; s.y += v.y; s.z += v.z; s.w += v.w;
    }
    s.x *= (1.0f / L); s.y *= (1.0f / L); s.z *= (1.0f / L); s.w *= (1.0f / L);
    ushort4 o;
    o.x = f2bf(s.x); o.y = f2bf(s.y); o.z = f2bf(s.z); o.w = f2bf(s.w);
    int off = (d4 >> 5) * 512 + w * 32 + (d4 & 31);
    *(ushort4*)&hA[off] = o;
    *(ushort4*)&h_sw[((size_t)(b * 64 + nt) * 8) * 512 + off] = o;
    __syncthreads();
    if (w < 4) wh_tile(hA, WT0, asrc0, adst0, WhT0, srcv0, dstv0, b, n0, w, lane);
}

// ---- k_attn_f: attention (wave=head, full m sweep) + LN + next-layer Wh fused ----
template <int FINAL>
__global__ __launch_bounds__(256) void k_attn_f(const unsigned long long* __restrict__ pack,
                                                const float* __restrict__ srcv_in,
                                                const float* __restrict__ dstv_in,
                                                const unsigned short* __restrict__ WhT_in,
                                                unsigned short* __restrict__ h_sw,
                                                const float* __restrict__ scale_l,
                                                const float* __restrict__ bias_l,
                                                const unsigned short* __restrict__ WT_next,
                                                const float* __restrict__ asrc_n,
                                                const float* __restrict__ adst_n,
                                                unsigned short* __restrict__ WhT_out,
                                                float* __restrict__ srcv_out,
                                                float* __restrict__ dstv_out,
                                                float* __restrict__ out) {
    // smem plan: [0,16384) dsts[4][1024] f32 ; [16384,18432) pack[16][16] u64
    //            after sync: [0,17152) xt[16][268] f32 ; [17408,25600) hA[8][16][32] bf16
    __shared__ __align__(16) char smem[25600];
    float* dsts = (float*)smem;
    unsigned long long* packs = (unsigned long long*)(smem + 16384);
    float* xt = (float*)smem;
    unsigned short* hA = (unsigned short*)(smem + 17408);

    int tid = threadIdx.x;
    int bt = blockIdx.x;
    int b = bt >> 6, nt = bt & 63, n0 = nt * 16;
    int w = tid >> 6, lane = tid & 63;      // w = head
    int rowLane = lane & 15, quad = lane >> 4;
    int bh = b * H + w;

    {
        const float* dv = dstv_in + (size_t)bh * N;
#pragma unroll
        for (int k = 0; k < 4; ++k)
            *(float4*)(dsts + w * 1024 + k * 256 + lane * 4) = *(const float4*)(dv + k * 256 + lane * 4);
        packs[tid] = pack[((size_t)(b * N + n0 + (tid >> 4))) * 16 + (tid & 15)];
    }
    __syncthreads();

    float src = srcv_in[bh * N + n0 + rowLane];
    float mx = src > 0.f ? src : 0.2f * src;           // per-row shift, cancels in softmax
    const unsigned* prow = (const unsigned*)packs + rowLane * 32;
    const unsigned short* wbase = WhT_in + (size_t)bh * 65536 + rowLane * 32 + quad * 8;
    const float* dw = dsts + w * 1024 + quad * 8;

    f32x4 acc[4] = {};
    float sum0 = 0.f, sum1 = 0.f;
    short8 fb[2][4];
#pragma unroll
    for (int c = 0; c < 4; ++c) fb[0][c] = *(const short8*)(wbase + c * 512);
#pragma unroll 2
    for (int t2 = 0; t2 < 32; ++t2) {
        int cb = t2 & 1;
        int t2n = (t2 + 1) & 31;
#pragma unroll
        for (int c = 0; c < 4; ++c)
            fb[cb ^ 1][c] = *(const short8*)(wbase + (size_t)t2n * 2048 + c * 512);
        unsigned bits = (prow[t2] >> (quad * 8)) & 0xffu;
        float4 d0 = *(const float4*)(dw + t2 * 32);
        float4 d1 = *(const float4*)(dw + t2 * 32 + 4);
        float dd[8] = {d0.x, d0.y, d0.z, d0.w, d1.x, d1.y, d1.z, d1.w};
        unsigned pk[4];
#pragma unroll
        for (int j2 = 0; j2 < 4; ++j2) {
            float ea = src + dd[2 * j2];
            float eb = src + dd[2 * j2 + 1];
            ea = ea > 0.f ? ea : 0.2f * ea;
            eb = eb > 0.f ? eb : 0.2f * eb;
            float pa = ((bits >> (2 * j2)) & 1) ? __expf(ea - mx) : 0.f;
            float pb = ((bits >> (2 * j2 + 1)) & 1) ? __expf(eb - mx) : 0.f;
            sum0 += pa; sum1 += pb;
            pk[j2] = (__float_as_uint(pb) & 0xffff0000u) | (__float_as_uint(pa) >> 16);
        }
        U8 u; u.u = make_uint4(pk[0], pk[1], pk[2], pk[3]);
        short8 af = u.s;
        acc[0] = __builtin_amdgcn_mfma_f32_16x16x32_bf16(af, fb[cb][0], acc[0], 0, 0, 0);
        acc[1] = __builtin_amdgcn_mfma_f32_16x16x32_bf16(af, fb[cb][1], acc[1], 0, 0, 0);
        acc[2] = __builtin_amdgcn_mfma_f32_16x16x32_bf16(af, fb[cb][2], acc[2], 0, 0, 0);
        acc[3] = __builtin_amdgcn_mfma_f32_16x16x32_bf16(af, fb[cb][3], acc[3], 0, 0, 0);
    }
    // full row sums (in-wave): lanes sharing rowLane across 4 quads cover all m
    float sum = sum0 + sum1;
    sum += __shfl_xor(sum, 16, 64);
    sum += __shfl_xor(sum, 32, 64);
    float inv[4];
#pragma unroll
    for (int r = 0; r < 4; ++r) inv[r] = 1.0f / __shfl(sum, quad * 4 + r, 64);

    __syncthreads();   // everyone done reading dsts/packs before xt overwrite
#pragma unroll
    for (int c = 0; c < 4; ++c)
#pragma unroll
        for (int r = 0; r < 4; ++r)
            xt[(quad * 4 + r) * 268 + w * 64 + c * 16 + rowLane] = acc[c][r] * inv[r];
    __syncthreads();

    // ---- LN: thread = (row = tid>>4, g = tid&15), 16 cols each ----
    int row = tid >> 4, g = tid & 15;
    size_t hsb = ((size_t)(b * 64 + nt) * 8 + (g >> 1)) * 512 + row * 32 + (g & 1) * 16;
    U8 r0, r1;
    r0.u = *(const uint4*)(h_sw + hsb);
    r1.u = *(const uint4*)(h_sw + hsb + 8);
    float4 xr[4];
#pragma unroll
    for (int k = 0; k < 4; ++k) xr[k] = *(const float4*)(xt + row * 268 + g * 16 + k * 4);
    float xv[16];
    float s = 0.f, s2 = 0.f;
#pragma unroll
    for (int j = 0; j < 16; ++j) {
        unsigned short hv = (j < 8) ? ((const unsigned short*)&r0)[j] : ((const unsigned short*)&r1)[j - 8];
        float x = bf2f(hv) + ((const float*)xr)[j];
        xv[j] = x; s += x; s2 += x * x;
    }
#pragma unroll
    for (int off = 1; off < 16; off <<= 1) {
        s += __shfl_xor(s, off, 64);
        s2 += __shfl_xor(s2, off, 64);
    }
    float mu = s * (1.0f / D);
    float var = s2 * (1.0f / D) - mu * mu;
    float rstd = rsqrtf(var + 1e-5f);
    int d0 = g * 16;
    if (FINAL) {
        float* orow = out + ((size_t)(b * N) + n0 + row) * D + d0;
#pragma unroll
        for (int k = 0; k < 4; ++k) {
            float4 sc = *(const float4*)(scale_l + d0 + k * 4);
            float4 bi = *(const float4*)(bias_l + d0 + k * 4);
            float4 y;
            y.x = (xv[k * 4 + 0] - mu) * rstd * sc.x + bi.x;
            y.y = (xv[k * 4 + 1] - mu) * rstd * sc.y + bi.y;
            y.z = (xv[k * 4 + 2] - mu) * rstd * sc.z + bi.z;
            y.w = (xv[k * 4 + 3] - mu) * rstd * sc.w + bi.w;
            *(float4*)(orow + k * 4) = y;
        }
    } else {
        U8 o0, o1;
#pragma unroll
        for (int j = 0; j < 16; ++j) {
            float scv = scale_l[d0 + j];
            float biv = bias_l[d0 + j];
            unsigned short yb = f2bf((xv[j] - mu) * rstd * scv + biv);
            if (j < 8) ((unsigned short*)&o0)[j] = yb;
            else ((unsigned short*)&o1)[j - 8] = yb;
        }
        *(uint4*)(h_sw + hsb) = o0.u;
        *(uint4*)(h_sw + hsb + 8) = o1.u;
        unsigned short* ha = hA + (g >> 1) * 512 + row * 32 + (g & 1) * 16;
        *(uint4*)ha = o0.u;
        *(uint4*)(ha + 8) = o1.u;
        __syncthreads();
        // ---- next-layer Wh fused: wave = head ----
        wh_tile(hA, WT_next, asrc_n, adst_n, WhT_out, srcv_out, dstv_out, b, n0, w, lane);
    }
}

extern "C" void kernel_launch(void* const* d_in, const int* in_sizes, int n_in,
                              void* d_out, int out_size, void* d_ws, size_t ws_size,
                              hipStream_t stream) {
    const int* cfg_adj = (const int*)d_in[0];
    const int* cfg_nodes = (const int*)d_in[1];
    const int* cfg_len = (const int*)d_in[2];
    const float* emb = (const float*)d_in[3];
    const float* W = (const float*)d_in[4];
    const float* a_src = (const float*)d_in[5];
    const float* a_dst = (const float*)d_in[6];
    const float* ln_scale = (const float*)d_in[7];
    const float* ln_bias = (const float*)d_in[8];
    float* out = (float*)d_out;
    float* ws = (float*)d_ws;

    float* srcv0 = ws;
    float* dstv0 = srcv0 + (size_t)B * H * N;
    float* srcv1 = dstv0 + (size_t)B * H * N;
    float* dstv1 = srcv1 + (size_t)B * H * N;
    unsigned short* h_sw = (unsigned short*)(dstv1 + (size_t)B * H * N);
    unsigned short* WhT0 = h_sw + (size_t)B * N * D;
    unsigned short* WhT1 = WhT0 + (size_t)B * H * DH * N;
    unsigned short* WT_sw = WhT1 + (size_t)B * H * DH * N;
    unsigned long long* pack = (unsigned long long*)(WT_sw + (size_t)NLAYERS * H * DH * D);

    k_pre<<<PRE_GRID, 256, 0, stream>>>(cfg_adj, W, cfg_len, pack, WT_sw, out + (size_t)B * N * D);
    k_feat<<<B * 64, 1024, 0, stream>>>(emb, cfg_nodes, h_sw, WT_sw, a_src, a_dst,
                                        WhT0, srcv0, dstv0);
    k_attn_f<0><<<B * 64, 256, 0, stream>>>(pack, srcv0, dstv0, WhT0, h_sw,
                                            ln_scale, ln_bias,
                                            WT_sw + (size_t)H * DH * D,
                                            a_src + (size_t)H * DH, a_dst + (size_t)H * DH,
                                            WhT1, srcv1, dstv1, nullptr);
    k_attn_f<1><<<B * 64, 256, 0, stream>>>(pack, srcv1, dstv1, WhT1, h_sw,
                                            ln_scale + D, ln_bias + D,
                                            nullptr, nullptr, nullptr,
                                            nullptr, nullptr, nullptr, out);
}